// Round 1
// baseline (571.176 us; speedup 1.0000x reference)
//
#include <hip/hip_runtime.h>
#include <math.h>

#define N_ATOMS 100000
#define N_EDGES 1600000
#define NSTRUCT 64

// ---------------- CSR build ----------------

__global__ void k_hist(const int* __restrict__ i_idx, int* __restrict__ counts) {
    int e = blockIdx.x * 256 + threadIdx.x;
    if (e < N_EDGES) atomicAdd(&counts[i_idx[e]], 1);
}

__global__ void k_blocksum(const int* __restrict__ counts, int* __restrict__ bsum) {
    __shared__ int sd[256];
    int a = blockIdx.x * 256 + threadIdx.x;
    sd[threadIdx.x] = (a < N_ATOMS) ? counts[a] : 0;
    __syncthreads();
    for (int off = 128; off > 0; off >>= 1) {
        if (threadIdx.x < off) sd[threadIdx.x] += sd[threadIdx.x + off];
        __syncthreads();
    }
    if (threadIdx.x == 0) bsum[blockIdx.x] = sd[0];
}

__global__ void k_scanb(const int* __restrict__ bsum, int* __restrict__ bpre, int nb) {
    if (threadIdx.x == 0) {
        int run = 0;
        for (int b = 0; b < nb; b++) { bpre[b] = run; run += bsum[b]; }
    }
}

__global__ void k_rowstart(const int* __restrict__ counts, const int* __restrict__ bpre,
                           int* __restrict__ row_start, int* __restrict__ cursor) {
    __shared__ int sd[256];
    int t = threadIdx.x;
    int a = blockIdx.x * 256 + t;
    int v = (a < N_ATOMS) ? counts[a] : 0;
    sd[t] = v;
    __syncthreads();
    for (int off = 1; off < 256; off <<= 1) {
        int add = (t >= off) ? sd[t - off] : 0;
        __syncthreads();
        sd[t] += add;
        __syncthreads();
    }
    if (a < N_ATOMS) {
        int excl = sd[t] - v + bpre[blockIdx.x];
        row_start[a] = excl;
        cursor[a] = excl;
    }
}

__global__ void k_scatter(const int* __restrict__ i_idx, int* __restrict__ cursor,
                          int* __restrict__ eids) {
    int e = blockIdx.x * 256 + threadIdx.x;
    if (e < N_EDGES) {
        int i = i_idx[e];
        int s = atomicAdd(&cursor[i], 1);
        eids[s] = e;
    }
}

// ---------------- edge accumulate (per-atom, registers) ----------------

__global__ __launch_bounds__(256) void k_edgeacc(
    const float* __restrict__ pos, const float* __restrict__ mmv,
    const int* __restrict__ species, const int* __restrict__ j_idx,
    const float* __restrict__ cheb,
    const int* __restrict__ row_start, const int* __restrict__ counts,
    const int* __restrict__ eids, float* __restrict__ segbuf) {
    int a = blockIdx.x * 256 + threadIdx.x;
    if (a >= N_ATOMS) return;

    float seg[8][8];
    float vc[8][3];
#pragma unroll
    for (int k = 0; k < 8; k++)
#pragma unroll
        for (int n = 0; n < 8; n++) seg[k][n] = 0.f;
#pragma unroll
    for (int n = 0; n < 8; n++) { vc[n][0] = 0.f; vc[n][1] = 0.f; vc[n][2] = 0.f; }

    float pix = pos[a * 3 + 0], piy = pos[a * 3 + 1], piz = pos[a * 3 + 2];
    float mix = mmv[a * 3 + 0], miy = mmv[a * 3 + 1], miz = mmv[a * 3 + 2];
    int spi = species[a];
    float mni = sqrtf(mix * mix + miy * miy + miz * miz + 1e-9f);
    float inv_mni = 1.f / mni;
    float mhix = mix * inv_mni, mhiy = miy * inv_mni, mhiz = miz * inv_mni;

    int start = row_start[a], cnt = counts[a];
    for (int s = 0; s < cnt; s++) {
        int e = eids[start + s];
        int j = j_idx[e];
        float pjx = pos[j * 3 + 0], pjy = pos[j * 3 + 1], pjz = pos[j * 3 + 2];
        float mjx = mmv[j * 3 + 0], mjy = mmv[j * 3 + 1], mjz = mmv[j * 3 + 2];
        int spj = species[j];

        float rx = pjx - pix, ry = pjy - piy, rz = pjz - piz;
        float d2 = rx * rx + ry * ry + rz * rz + 1e-9f;
        float d = sqrtf(d2);
        float invd = 1.f / d;
        float rhx = rx * invd, rhy = ry * invd, rhz = rz * invd;

        float x = d * (1.f / 3.f) - 1.f;
        x = fminf(fmaxf(x, -1.f), 1.f);
        float T[12];
        T[0] = 1.f; T[1] = x;
#pragma unroll
        for (int k = 2; k < 12; k++) T[k] = 2.f * x * T[k - 1] - T[k - 2];
        float fcut = (d < 6.f) ? 0.5f * (__cosf(d * 0.52359877559829887f) + 1.f) : 0.f;

        const float* crow = cheb + (spi * 4 + spj) * 96;
        float phi[8];
#pragma unroll
        for (int n = 0; n < 8; n++) {
            const float4* c4 = (const float4*)(crow + n * 12);
            float4 c0 = c4[0], c1 = c4[1], c2 = c4[2];
            float acc = c0.x * T[0] + c0.y * T[1] + c0.z * T[2] + c0.w * T[3];
            acc += c1.x * T[4] + c1.y * T[5] + c1.z * T[6] + c1.w * T[7];
            acc += c2.x * T[8] + c2.y * T[9] + c2.z * T[10] + c2.w * T[11];
            phi[n] = acc * fcut;
        }

        float mnj = sqrtf(mjx * mjx + mjy * mjy + mjz * mjz + 1e-9f);
        float invmnj = 1.f / mnj;
        float mhjx = mjx * invmnj, mhjy = mjy * invmnj, mhjz = mjz * invmnj;

        float w[8];
        w[0] = 1.f;
        w[1] = mix * mjx + miy * mjy + miz * mjz;
        float dhi = mhix * rhx + mhiy * rhy + mhiz * rhz;
        w[2] = dhi * dhi;
        float dhj = mhjx * rhx + mhjy * rhy + mhjz * rhz;
        w[3] = dhj * dhj;
        float cx = miy * mjz - miz * mjy;
        float cy = miz * mjx - mix * mjz;
        float cz = mix * mjy - miy * mjx;
        w[4] = rhx * cx + rhy * cy + rhz * cz;
        w[5] = mnj;
        w[6] = (mhix * mhjx + mhiy * mhjy + mhiz * mhjz) * mnj;
        w[7] = mnj * mnj;

#pragma unroll
        for (int k = 0; k < 8; k++)
#pragma unroll
            for (int n = 0; n < 8; n++) seg[k][n] = fmaf(w[k], phi[n], seg[k][n]);
#pragma unroll
        for (int n = 0; n < 8; n++) {
            vc[n][0] = fmaf(phi[n], rhx, vc[n][0]);
            vc[n][1] = fmaf(phi[n], rhy, vc[n][1]);
            vc[n][2] = fmaf(phi[n], rhz, vc[n][2]);
        }
    }

    float* o = segbuf + (size_t)a * 72;
#pragma unroll
    for (int k = 0; k < 8; k++)
#pragma unroll
        for (int n = 0; n < 8; n++) o[k * 8 + n] = seg[k][n];
#pragma unroll
    for (int n = 0; n < 8; n++)
        o[64 + n] = vc[n][0] * vc[n][0] + vc[n][1] * vc[n][1] + vc[n][2] * vc[n][2];
}

// ---------------- per-atom MLPs + structure reduction ----------------

__global__ __launch_bounds__(256) void k_mlp(
    const float* __restrict__ segbuf, const float* __restrict__ mmv,
    const int* __restrict__ species, const int* __restrict__ batch,
    const float* __restrict__ embt, const float* __restrict__ shift,
    const float* __restrict__ Ws1, const float* __restrict__ bs1,
    const float* __restrict__ Ws2, const float* __restrict__ bs2,
    const float* __restrict__ Ws3, const float* __restrict__ bs3,
    const float* __restrict__ Wm1, const float* __restrict__ bm1,
    const float* __restrict__ Wm2, const float* __restrict__ bm2,
    const float* __restrict__ Wm3, const float* __restrict__ bm3,
    float* __restrict__ out) {
    __shared__ float spart[NSTRUCT];
    int t = threadIdx.x;
    if (t < NSTRUCT) spart[t] = 0.f;
    __syncthreads();

    int a = blockIdx.x * 256 + t;
    if (a < N_ATOMS) {
        const float* sb = segbuf + (size_t)a * 72;
        int spi = species[a];
        float emb[16];
#pragma unroll
        for (int q = 0; q < 16; q++) emb[q] = embt[spi * 16 + q];

        float x[32];
#pragma unroll
        for (int n = 0; n < 8; n++) x[n] = sb[n];        // A = seg row k=0
#pragma unroll
        for (int n = 0; n < 8; n++) x[8 + n] = sb[64 + n]; // |vec|^2
#pragma unroll
        for (int q = 0; q < 16; q++) x[16 + q] = emb[q];

        float h1[64];
#pragma unroll
        for (int o = 0; o < 64; o++) h1[o] = bs1[o];
        for (int k = 0; k < 32; k++) {
            float xv = x[k];
#pragma unroll
            for (int o = 0; o < 64; o++) h1[o] = fmaf(xv, Ws1[k * 64 + o], h1[o]);
        }
#pragma unroll
        for (int o = 0; o < 64; o++) { float v = h1[o]; h1[o] = v / (1.f + __expf(-v)); }

        float h2[64];
#pragma unroll
        for (int o = 0; o < 64; o++) h2[o] = bs2[o];
        for (int k = 0; k < 64; k++) {
            float xv = h1[k];
#pragma unroll
            for (int o = 0; o < 64; o++) h2[o] = fmaf(xv, Ws2[k * 64 + o], h2[o]);
        }
        float e_struct = bs3[0];
#pragma unroll
        for (int o = 0; o < 64; o++) {
            float v = h2[o];
            v = v / (1.f + __expf(-v));
            e_struct = fmaf(v, Ws3[o], e_struct);
        }

        float mx = mmv[a * 3 + 0], my = mmv[a * 3 + 1], mz = mmv[a * 3 + 2];
        float amp = sqrtf(mx * mx + my * my + mz * mz + 1e-9f);

        float e_mag = 0.f;
        for (int h = 0; h < 9; h++) {
            int kk = (h <= 5) ? h : (h - 1);
            float scale = (h == 0 || h == 5) ? amp : 1.f;
            float xm[8];
#pragma unroll
            for (int n = 0; n < 8; n++) xm[n] = sb[kk * 8 + n] * scale;

            float hm1[32];
#pragma unroll
            for (int o = 0; o < 32; o++) hm1[o] = bm1[h * 32 + o];
            for (int dd = 0; dd < 8; dd++) {
                float xv = xm[dd];
#pragma unroll
                for (int o = 0; o < 32; o++) hm1[o] = fmaf(xv, Wm1[(h * 24 + dd) * 32 + o], hm1[o]);
            }
            for (int dd = 0; dd < 16; dd++) {
                float xv = emb[dd];
#pragma unroll
                for (int o = 0; o < 32; o++) hm1[o] = fmaf(xv, Wm1[(h * 24 + 8 + dd) * 32 + o], hm1[o]);
            }
#pragma unroll
            for (int o = 0; o < 32; o++) { float v = hm1[o]; hm1[o] = v / (1.f + __expf(-v)); }

            float hm2[32];
#pragma unroll
            for (int o = 0; o < 32; o++) hm2[o] = bm2[h * 32 + o];
            for (int dd = 0; dd < 32; dd++) {
                float xv = hm1[dd];
#pragma unroll
                for (int o = 0; o < 32; o++) hm2[o] = fmaf(xv, Wm2[(h * 32 + dd) * 32 + o], hm2[o]);
            }
            float acc = bm3[h];
#pragma unroll
            for (int o = 0; o < 32; o++) {
                float v = hm2[o];
                v = v / (1.f + __expf(-v));
                acc = fmaf(v, Wm3[h * 32 + o], acc);
            }
            e_mag += acc;
        }

        float e_atom = e_struct + e_mag + shift[spi];
        atomicAdd(&spart[batch[a]], e_atom);
    }
    __syncthreads();
    if (t < NSTRUCT) {
        float v = spart[t];
        if (v != 0.f) atomicAdd(&out[t], v);
    }
}

// ---------------- launch ----------------

extern "C" void kernel_launch(void* const* d_in, const int* in_sizes, int n_in,
                              void* d_out, int out_size, void* d_ws, size_t ws_size,
                              hipStream_t stream) {
    const float* pos   = (const float*)d_in[0];
    const float* mmv   = (const float*)d_in[1];
    const int* species = (const int*)d_in[2];
    const int* i_idx   = (const int*)d_in[3];
    const int* j_idx   = (const int*)d_in[4];
    const int* batch   = (const int*)d_in[5];
    const float* cheb  = (const float*)d_in[6];
    const float* embt  = (const float*)d_in[7];
    const float* shift = (const float*)d_in[8];
    const float* Ws1 = (const float*)d_in[9];
    const float* bs1 = (const float*)d_in[10];
    const float* Ws2 = (const float*)d_in[11];
    const float* bs2 = (const float*)d_in[12];
    const float* Ws3 = (const float*)d_in[13];
    const float* bs3 = (const float*)d_in[14];
    const float* Wm1 = (const float*)d_in[15];
    const float* bm1 = (const float*)d_in[16];
    const float* Wm2 = (const float*)d_in[17];
    const float* bm2 = (const float*)d_in[18];
    const float* Wm3 = (const float*)d_in[19];
    const float* bm3 = (const float*)d_in[20];
    float* out = (float*)d_out;

    char* ws = (char*)d_ws;
    int* counts    = (int*)(ws + 0);        // 400000 B
    int* row_start = (int*)(ws + 400384);   // 400000 B
    int* cursor    = (int*)(ws + 800768);   // 400000 B
    int* bsum      = (int*)(ws + 1201152);  // 1600 B
    int* bpre      = (int*)(ws + 1202816);  // 1600 B
    int* eids      = (int*)(ws + 1204480);  // 6.4 MB
    float* segbuf  = (float*)(ws + 7604480); // 28.8 MB (end ~36.4 MB)

    const int NB_ATOM = (N_ATOMS + 255) / 256;   // 391
    const int NB_EDGE = (N_EDGES + 255) / 256;   // 6250

    hipMemsetAsync(counts, 0, N_ATOMS * sizeof(int), stream);
    hipMemsetAsync(out, 0, NSTRUCT * sizeof(float), stream);

    k_hist<<<NB_EDGE, 256, 0, stream>>>(i_idx, counts);
    k_blocksum<<<NB_ATOM, 256, 0, stream>>>(counts, bsum);
    k_scanb<<<1, 64, 0, stream>>>(bsum, bpre, NB_ATOM);
    k_rowstart<<<NB_ATOM, 256, 0, stream>>>(counts, bpre, row_start, cursor);
    k_scatter<<<NB_EDGE, 256, 0, stream>>>(i_idx, cursor, eids);
    k_edgeacc<<<NB_ATOM, 256, 0, stream>>>(pos, mmv, species, j_idx, cheb,
                                           row_start, counts, eids, segbuf);
    k_mlp<<<NB_ATOM, 256, 0, stream>>>(segbuf, mmv, species, batch, embt, shift,
                                       Ws1, bs1, Ws2, bs2, Ws3, bs3,
                                       Wm1, bm1, Wm2, bm2, Wm3, bm3, out);
}